// Round 4
// baseline (854.067 us; speedup 1.0000x reference)
//
#include <hip/hip_runtime.h>
#include <hip/hip_bf16.h>

typedef __attribute__((ext_vector_type(8))) short bf16x8;
typedef __attribute__((ext_vector_type(4))) float f32x4;
typedef __attribute__((ext_vector_type(4))) float fvec4;
typedef unsigned short u16;
typedef unsigned int u32;
typedef unsigned long long u64;

#define N_TOK 131072

__device__ __forceinline__ u16 f2bf(float f) {
  u32 u = __builtin_bit_cast(u32, f);
  u += 0x7FFFu + ((u >> 16) & 1u);          // round-to-nearest-even
  return (u16)(u >> 16);
}

__device__ __forceinline__ f32x4 mfma16(bf16x8 a, bf16x8 b, f32x4 c) {
  return __builtin_amdgcn_mfma_f32_16x16x32_bf16(a, b, c, 0, 0, 0);
}

// swizzled index into [rows][128 shorts] LDS tile: 16B-chunk XOR row&15
__device__ __forceinline__ int tix(int row, int s) {
  return (row << 7) + ((((s >> 3) ^ (row & 15))) << 3) + (s & 7);
}
// swizzled index into [rows][64 shorts] LDS tile: 16B-chunk XOR row&7
__device__ __forceinline__ int tix64(int row, int s) {
  return (row << 6) + ((((s >> 3) ^ (row & 7))) << 3) + (s & 7);
}

// direct global->LDS (16B per lane, wave-uniform LDS base + lane*16 by HW)
__device__ __forceinline__ void gll16(const void* g, void* l) {
  __builtin_amdgcn_global_load_lds(
      (const __attribute__((address_space(1))) unsigned int*)g,
      (__attribute__((address_space(3))) unsigned int*)l, 16, 0, 0);
}
// stage a 16KB pre-swizzled weight image into LDS (4 calls/wave x 1KB)
__device__ __forceinline__ void stage_img(u16* lds, const u16* img, int wave, int lane) {
#pragma unroll
  for (int j = 0; j < 4; ++j) {
    const int off = ((wave << 2) + j) << 10;   // bytes
    gll16((const char*)img + off + (lane << 4), (char*)lds + off);
  }
}

// ---------------------------------------------------------------------------
// Weight prep: bf16, transposed, PRE-SWIZZLED into LDS image order.
//  WqkvI [which][half] 16KB images: tix layout [64 rows=e_local][128 k]
//  WpI   [k-half]      16KB images: tix64 layout [128 rows=out-col][64 k]
//  W1I   [chunk 0..7]  16KB images: tix layout [64 rows=hcol_local][128 k]
//  W2T   [col][512 k]  linear bf16 (read as global fragments)
// ---------------------------------------------------------------------------
__global__ __launch_bounds__(256) void prep_kernel(
    const float* __restrict__ Wqkv, const float* __restrict__ bqkv,
    const float* __restrict__ Wproj, const float* __restrict__ W1,
    const float* __restrict__ W2,
    u16* __restrict__ WqI, u16* __restrict__ WpI,
    u16* __restrict__ W1I, u16* __restrict__ W2T,
    float* __restrict__ bqp)
{
  const int idx = blockIdx.x * 256 + threadIdx.x;
  const int PER = 196608;
  if (idx < 3 * PER) {
    const int d = idx / PER, r = idx % PER;
    if (r < 49152) {                       // WqkvI
      const int which = r / 16384, rem = r % 16384;
      const int h = rem >> 13, off = rem & 8191;
      const int row = off >> 7;
      const int k = ((((off >> 3) & 15) ^ (row & 15)) << 3) | (off & 7);
      const int e = (h << 6) + row;
      WqI[d * 49152 + r] = f2bf(Wqkv[(size_t)d * 49152 + k * 384 + e * 3 + which]);
    } else if (r < 65536) {                // WpI (tix64 k-half images)
      const int r2 = r - 49152;
      const int h = r2 >> 13, off = r2 & 8191;
      const int col = off >> 6;
      const int kl = ((((off >> 3) & 7) ^ (col & 7)) << 3) | (off & 7);
      WpI[d * 16384 + r2] = f2bf(Wproj[(size_t)d * 16384 + ((h << 6) + kl) * 128 + col]);
    } else if (r < 131072) {               // W1I (tix chunk images)
      const int r3 = r - 65536;
      const int c = r3 >> 13, off = r3 & 8191;
      const int row = off >> 7;
      const int k = ((((off >> 3) & 15) ^ (row & 15)) << 3) | (off & 7);
      W1I[d * 65536 + r3] = f2bf(W1[(size_t)d * 65536 + k * 512 + (c << 6) + row]);
    } else {                               // W2T[col][512] linear
      const int r4 = r - 131072; const int col = r4 >> 9, k = r4 & 511;
      W2T[d * 65536 + r4] = f2bf(W2[(size_t)d * 65536 + k * 128 + col]);
    }
  } else if (idx < 3 * PER + 1152) {
    const int i2 = idx - 3 * PER; const int d = i2 / 384, c = i2 % 384;
    bqp[i2] = bqkv[d * 384 + (c & 127) * 3 + (c >> 7)];
  }
}

// ---------------------------------------------------------------------------
// img [128][131072] f32 -> x [131072][128] f32, with fused LN1-layer0 stats
// ---------------------------------------------------------------------------
__global__ __launch_bounds__(256) void tin_kernel(const float* __restrict__ img,
                                                  float* __restrict__ x,
                                                  float* __restrict__ accum)
{
  __shared__ float t[128 * 65];
  __shared__ float ssum[256], sqq[256];
  const int t0 = blockIdx.x * 64;
  const int tid = threadIdx.x;
  {
    const int j = tid & 63, cq = tid >> 6;
    for (int c = cq; c < 128; c += 4) t[c * 65 + j] = img[(size_t)c * N_TOK + t0 + j];
  }
  __syncthreads();
  {
    const int c = tid & 127, jh = tid >> 7;
    float s = 0.f, q = 0.f;
    for (int jj = jh; jj < 64; jj += 2) {
      const float v = t[c * 65 + jj];
      x[(size_t)(t0 + jj) * 128 + c] = v;
      s += v; q += v * v;
    }
    ssum[tid] = s; sqq[tid] = q;
  }
  __syncthreads();
  if (tid < 128) {
    atomicAdd(&accum[tid], ssum[tid] + ssum[tid + 128]);
    atomicAdd(&accum[128 + tid], sqq[tid] + sqq[tid + 128]);
  }
}

// x [131072][128] -> out [128][131072] with relu
__global__ __launch_bounds__(256) void tout_kernel(const float* __restrict__ x,
                                                   float* __restrict__ out)
{
  __shared__ float t[128 * 65];
  const int t0 = blockIdx.x * 64;
  const int tid = threadIdx.x;
  {
    const int c = tid & 127, jh = tid >> 7;
    for (int jj = jh; jj < 64; jj += 2) t[c * 65 + jj] = x[(size_t)(t0 + jj) * 128 + c];
  }
  __syncthreads();
  {
    const int j = tid & 63, cq = tid >> 6;
    for (int c = cq; c < 128; c += 4)
      out[(size_t)c * N_TOK + t0 + j] = fmaxf(t[c * 65 + j], 0.f);
  }
}

__global__ void finalize_kernel(const float* __restrict__ accum, const float* __restrict__ g,
                                const float* __restrict__ b, float* __restrict__ st)
{
  const int c = threadIdx.x;
  const float inv = 1.f / 131072.f;
  const float mu = accum[c] * inv;
  const float var = accum[128 + c] * inv - mu * mu;
  const float s = g[c] * rsqrtf(var + 1e-5f);
  st[c] = s;
  st[128 + c] = b[c] - mu * s;
}

// ---------------------------------------------------------------------------
// Device helpers
// ---------------------------------------------------------------------------
__device__ __forceinline__ void ln_load_afrags(const float* __restrict__ x0,
                                               const float* __restrict__ x1,
                                               const float* __restrict__ st,
                                               int lg, bf16x8 aF[2][4]) {
#pragma unroll
  for (int kk = 0; kk < 4; ++kk) {
    const int k0 = (kk << 5) + (lg << 3);
    const fvec4 sA = *(const fvec4*)(st + k0);
    const fvec4 sB = *(const fvec4*)(st + k0 + 4);
    const fvec4 tA = *(const fvec4*)(st + 128 + k0);
    const fvec4 tB = *(const fvec4*)(st + 128 + k0 + 4);
    {
      const fvec4 v0 = *(const fvec4*)(x0 + k0);
      const fvec4 v1 = *(const fvec4*)(x0 + k0 + 4);
      bf16x8 w;
#pragma unroll
      for (int j = 0; j < 4; ++j) w[j] = (short)f2bf(v0[j] * sA[j] + tA[j]);
#pragma unroll
      for (int j = 0; j < 4; ++j) w[4 + j] = (short)f2bf(v1[j] * sB[j] + tB[j]);
      aF[0][kk] = w;
    }
    {
      const fvec4 v0 = *(const fvec4*)(x1 + k0);
      const fvec4 v1 = *(const fvec4*)(x1 + k0 + 4);
      bf16x8 w;
#pragma unroll
      for (int j = 0; j < 4; ++j) w[j] = (short)f2bf(v0[j] * sA[j] + tA[j]);
#pragma unroll
      for (int j = 0; j < 4; ++j) w[4 + j] = (short)f2bf(v1[j] * sB[j] + tB[j]);
      aF[1][kk] = w;
    }
  }
}

// acc[2][4] = Aregs(32 rows x 128k) @ B-chunk(64 cols x 128k, tix)
__device__ __forceinline__ void gemm_rA_B64(const bf16x8 aF[2][4], const u16* __restrict__ B,
                                            int lr, int lg, f32x4 acc[2][4]) {
#pragma unroll
  for (int mt = 0; mt < 2; ++mt)
#pragma unroll
    for (int n = 0; n < 4; ++n) acc[mt][n] = (f32x4){0.f, 0.f, 0.f, 0.f};
#pragma unroll
  for (int kk = 0; kk < 4; ++kk) {
    const int ks = (kk << 5) + (lg << 3);
    bf16x8 bfr[4];
#pragma unroll
    for (int n = 0; n < 4; ++n)
      bfr[n] = *(const bf16x8*)&B[tix((n << 4) + lr, ks)];
#pragma unroll
    for (int mt = 0; mt < 2; ++mt)
#pragma unroll
      for (int n = 0; n < 4; ++n)
        acc[mt][n] = mfma16(aF[mt][kk], bfr[n], acc[mt][n]);
  }
}

// acc[2][8] += A[128 rows][64 k](tix64, wave rows) @ B[128 cols][64 k](tix64)
__device__ __forceinline__ void gemm_A64_B128(const u16* __restrict__ A, const u16* __restrict__ B,
                                              int woff, int lr, int lg, f32x4 acc[2][8]) {
#pragma unroll
  for (int kk = 0; kk < 2; ++kk) {
    const int ks = (kk << 5) + (lg << 3);
    bf16x8 af[2], bfr[8];
#pragma unroll
    for (int mt = 0; mt < 2; ++mt)
      af[mt] = *(const bf16x8*)&A[tix64(woff + (mt << 4) + lr, ks)];
#pragma unroll
    for (int n = 0; n < 8; ++n)
      bfr[n] = *(const bf16x8*)&B[tix64((n << 4) + lr, ks)];
#pragma unroll
    for (int mt = 0; mt < 2; ++mt)
#pragma unroll
      for (int n = 0; n < 8; ++n)
        acc[mt][n] = mfma16(af[mt], bfr[n], acc[mt][n]);
  }
}

// write K/Q 64-col half into [128 rows=head*32+z][64] tix64 tile
__device__ __forceinline__ void write_kq(u16* __restrict__ R, const f32x4 acc[2][4],
                                         const float* __restrict__ bias,
                                         int wave, int lr, int lg) {
#pragma unroll
  for (int n = 0; n < 4; ++n) {
    const int el = (n << 4) + lr;
    const float bb = bias[el];
#pragma unroll
    for (int mt = 0; mt < 2; ++mt)
#pragma unroll
      for (int rr = 0; rr < 4; ++rr) {
        const int row = (rr << 5) + (wave << 3) + (mt << 2) + lg;
        R[tix64(row, el)] = f2bf(acc[mt][n][rr] + bb);
      }
  }
}

// ---------------------------------------------------------------------------
// Fused attention half-layer: block = 4 heads x 32 z = 128 tokens, 4 waves.
// Regions (16KB each): RA/RB weight dbl-buffer, R2 = K-half | vT,
// R3 = Q-half | attL | aout. All weight stages prefetched via gload_lds.
// ---------------------------------------------------------------------------
__global__ __launch_bounds__(256) void attn_fused_kernel(
    const u16* __restrict__ WqkvI,        // [3 which][2 half] 16KB images
    const float* __restrict__ bqp,        // [384]
    const u16* __restrict__ WpI,          // [2 k-half] 16KB images
    const float* __restrict__ bp,         // [128]
    const float* __restrict__ st,         // [256] LN1 fold
    float* __restrict__ accum,            // [256] LN2 stats out
    float* __restrict__ x)                // [131072][128] read + update
{
  __shared__ u16 RA[8192], RB[8192], R2[8192], R3[8192];
  __shared__ float sred[256];

  const int tid = threadIdx.x;
  const int lane = tid & 63, wave = tid >> 6;
  const int lr = lane & 15, lg = lane >> 4;
  const int h0 = blockIdx.x << 2;
  const int woff = wave << 5;

  sred[tid] = 0.f;

  const u16* WqI0 = WqkvI;            // [2 halves]
  const u16* WkI0 = WqkvI + 16384;
  const u16* WvI0 = WqkvI + 32768;

  // prologue: stage Wk0/Wq0 while loading+folding A fragments
  stage_img(RA, WkI0, wave, lane);
  stage_img(RB, WqI0, wave, lane);

  const int r0a = woff + lr, r1a = woff + 16 + lr;
  const int g0 = ((r0a >> 2) << 12) + h0 + (r0a & 3);
  const int g1 = ((r1a >> 2) << 12) + h0 + (r1a & 3);
  bf16x8 aF[2][4];
  ln_load_afrags(x + ((size_t)g0 << 7), x + ((size_t)g1 << 7), st, lg, aF);

  f32x4 et[2][2];
#pragma unroll
  for (int mt = 0; mt < 2; ++mt)
#pragma unroll
    for (int nt = 0; nt < 2; ++nt) et[mt][nt] = (f32x4){0.f, 0.f, 0.f, 0.f};

  __syncthreads();                                          // b0: Wk0,Wq0 ready

  // ---- QK half 0 ----
  {
    f32x4 kacc[2][4];
    gemm_rA_B64(aF, RA, lr, lg, kacc);
    write_kq(R2, kacc, bqp + 128, wave, lr, lg);
    f32x4 qacc[2][4];
    gemm_rA_B64(aF, RB, lr, lg, qacc);
    write_kq(R3, qacc, bqp, wave, lr, lg);
  }
  __syncthreads();                                          // b1: K0,Q0 visible
  stage_img(RA, WkI0 + 8192, wave, lane);                   // prefetch Wk1
  stage_img(RB, WqI0 + 8192, wave, lane);                   // prefetch Wq1
  {
    bf16x8 ka[2][2], qb2[2][2];
#pragma unroll
    for (int t = 0; t < 2; ++t)
#pragma unroll
      for (int kt = 0; kt < 2; ++kt) {
        const int row = (wave << 5) + (t << 4) + lr;
        const int ks = (kt << 5) + (lg << 3);
        ka[t][kt]  = *(const bf16x8*)&R2[tix64(row, ks)];
        qb2[t][kt] = *(const bf16x8*)&R3[tix64(row, ks)];
      }
#pragma unroll
    for (int kt = 0; kt < 2; ++kt)
#pragma unroll
      for (int mt = 0; mt < 2; ++mt)
#pragma unroll
        for (int nt = 0; nt < 2; ++nt)
          et[mt][nt] = mfma16(ka[mt][kt], qb2[nt][kt], et[mt][nt]);
  }
  __syncthreads();                                          // b2: E^T h0 done, Wk1/Wq1 ready

  // ---- QK half 1 ----
  {
    f32x4 kacc[2][4];
    gemm_rA_B64(aF, RA, lr, lg, kacc);
    write_kq(R2, kacc, bqp + 128 + 64, wave, lr, lg);
    f32x4 qacc[2][4];
    gemm_rA_B64(aF, RB, lr, lg, qacc);
    write_kq(R3, qacc, bqp + 64, wave, lr, lg);
  }
  __syncthreads();                                          // b3: K1,Q1 visible
  stage_img(RA, WvI0, wave, lane);                          // prefetch Wv0
  stage_img(RB, WpI, wave, lane);                           // prefetch Wp k-half 0
  {
    bf16x8 ka[2][2], qb2[2][2];
#pragma unroll
    for (int t = 0; t < 2; ++t)
#pragma unroll
      for (int kt = 0; kt < 2; ++kt) {
        const int row = (wave << 5) + (t << 4) + lr;
        const int ks = (kt << 5) + (lg << 3);
        ka[t][kt]  = *(const bf16x8*)&R2[tix64(row, ks)];
        qb2[t][kt] = *(const bf16x8*)&R3[tix64(row, ks)];
      }
#pragma unroll
    for (int kt = 0; kt < 2; ++kt)
#pragma unroll
      for (int mt = 0; mt < 2; ++mt)
#pragma unroll
        for (int nt = 0; nt < 2; ++nt)
          et[mt][nt] = mfma16(ka[mt][kt], qb2[nt][kt], et[mt][nt]);
  }

  // ---- softmax over kz, /sqrt(128), *cm (verified) ----
  float p[2][2][4];
#pragma unroll
  for (int nt = 0; nt < 2; ++nt) {
    float mx = -1e30f;
#pragma unroll
    for (int mt = 0; mt < 2; ++mt)
#pragma unroll
      for (int r = 0; r < 4; ++r) mx = fmaxf(mx, et[mt][nt][r]);
    mx = fmaxf(mx, __shfl_xor(mx, 16));
    mx = fmaxf(mx, __shfl_xor(mx, 32));
    float s = 0.f;
#pragma unroll
    for (int mt = 0; mt < 2; ++mt)
#pragma unroll
      for (int r = 0; r < 4; ++r) {
        const float e = __expf(et[mt][nt][r] - mx);
        p[mt][nt][r] = e;
        s += e;
      }
    s += __shfl_xor(s, 16);
    s += __shfl_xor(s, 32);
    const float inv = 1.f / (s * 11.313708498984761f);
    const int qz = (nt << 4) + lr;
#pragma unroll
    for (int mt = 0; mt < 2; ++mt)
#pragma unroll
      for (int r = 0; r < 4; ++r) {
        const int kz = (mt << 4) + (lg << 2) + r;
        const float d = (float)(kz - qz);
        p[mt][nt][r] *= inv * __expf(d * d * (-1.f / 16.f));
      }
  }

  // P^T -> attL (wave's own quarter of R3; same-wave write->read)
  u16* attLb = R3 + (wave << 11);
#pragma unroll
  for (int nt = 0; nt < 2; ++nt) {
    const int q = (nt << 4) + lr;
    const int qs = (q >> 1) & 3;
#pragma unroll
    for (int mt = 0; mt < 2; ++mt) {
      const int hc = (mt << 2) + lg;
      const int ch = (hc >> 1) ^ qs;
      const u32 lo = (u32)f2bf(p[mt][nt][0]) | ((u32)f2bf(p[mt][nt][1]) << 16);
      const u32 hi = (u32)f2bf(p[mt][nt][2]) | ((u32)f2bf(p[mt][nt][3]) << 16);
      *(u64*)&attLb[(q << 5) + (ch << 3) + ((hc & 1) << 2)] = (u64)lo | ((u64)hi << 32);
    }
  }
  bf16x8 pa[2];
#pragma unroll
  for (int mt = 0; mt < 2; ++mt) {
    const int q = (mt << 4) + lr;
    pa[mt] = *(const bf16x8*)&attLb[(q << 5) + ((lg ^ ((q >> 1) & 3)) << 3)];
  }
  __syncthreads();                                          // b4: pa extracted, Wv0/Wp0 ready

  f32x4 pacc[2][8];
#pragma unroll
  for (int mt = 0; mt < 2; ++mt)
#pragma unroll
    for (int n = 0; n < 8; ++n) pacc[mt][n] = (f32x4){0.f, 0.f, 0.f, 0.f};

  // ---- V / PV / proj, two e-halves ----
#pragma unroll 1
  for (int vh = 0; vh < 2; ++vh) {
    {  // V = A @ Wv_half -> vT (R2)
      f32x4 vacc[2][4];
      gemm_rA_B64(aF, RA, lr, lg, vacc);
      const float* bv = bqp + 256 + (vh << 6);
#pragma unroll
      for (int n = 0; n < 4; ++n) {
        const int el = (n << 4) + lr;
        const float bb = bv[el];
        const int sw = (el >> 1) & 3;
#pragma unroll
        for (int mt = 0; mt < 2; ++mt) {
          const int kzl = (mt << 2) + lg;
#pragma unroll
          for (int rr = 0; rr < 4; ++rr)
            R2[(rr << 11) + (el << 5) + ((wave ^ sw) << 3) + kzl] = f2bf(vacc[mt][n][rr] + bb);
        }
      }
    }
    __syncthreads();                                        // b5/b8: vT visible
    // PV half (head = wave) -> aout (R3)
#pragma unroll
    for (int n = 0; n < 4; ++n) {
      const int el = (n << 4) + lr;
      const bf16x8 vb = *(const bf16x8*)&R2[(wave << 11) + (el << 5) + ((lg ^ ((el >> 1) & 3)) << 3)];
      f32x4 o0, o1;
      {
        const f32x4 z4 = (f32x4){0.f, 0.f, 0.f, 0.f};
        o0 = mfma16(pa[0], vb, z4);
        o1 = mfma16(pa[1], vb, z4);
      }
#pragma unroll
      for (int rr = 0; rr < 4; ++rr) {
        const int q0 = (lg << 2) + rr;
        R3[tix64((q0 << 2) + wave, el)] = f2bf(o0[rr]);
        R3[tix64(((q0 + 16) << 2) + wave, el)] = f2bf(o1[rr]);
      }
    }
    if (vh == 0) {
      stage_img(RA, WvI0 + 8192, wave, lane);               // prefetch Wv1 (RA free: V0 read done by this wave)
      __syncthreads();                                      // b6: aout visible, Wp0 ready
      gemm_A64_B128(R3, RB, woff, lr, lg, pacc);            // proj k-half 0
      __syncthreads();                                      // b7: proj0 reads done, Wv1 ready
      stage_img(RB, WpI + 8192, wave, lane);                // prefetch Wp1 (RB free after b7)
    } else {
      __syncthreads();                                      // b9: aout visible, Wp1 ready
      gemm_A64_B128(R3, RB, woff, lr, lg, pacc);            // proj k-half 1
    }
  }

  // ---- epilogue: residual + LN2 stats ----
#pragma unroll
  for (int n = 0; n < 8; ++n) {
    const int col = (n << 4) + lr;
    const float bb = bp[col];
    float ssum = 0.f, qsum = 0.f;
#pragma unroll
    for (int mt = 0; mt < 2; ++mt) {
#pragma unroll
      for (int rr = 0; rr < 4; ++rr) {
        const int rl = woff + (mt << 4) + (lg << 2) + rr;
        const int grow = ((rl >> 2) << 12) + h0 + (rl & 3);
        const size_t gi = ((size_t)grow << 7) + col;
        const float v = pacc[mt][n][rr] + bb + x[gi];
        x[gi] = v;
        ssum += v; qsum += v * v;
      }
    }
    atomicAdd(&sred[col], ssum);
    atomicAdd(&sred[128 + col], qsum);
  }
  __syncthreads();
  atomicAdd(&accum[tid], sred[tid]);
}

// ---------------------------------------------------------------------------
// Fused FFN half-layer: block = 128 rows, 4 waves, LDS 49KB.
// W1 chunks prefetched (gload_lds double-buffer); W2 fragments from L2.
// ---------------------------------------------------------------------------
__global__ __launch_bounds__(256) void ffn_fused_kernel(
    const u16* __restrict__ W1I,    // [8 chunks] 16KB tix images
    const float* __restrict__ b1,   // [512]
    const u16* __restrict__ W2T,    // [128 col][512 k] linear bf16
    const float* __restrict__ b2,   // [128]
    const float* __restrict__ st,   // [256] LN2 fold
    float* __restrict__ accum,      // [256] next LN1 stats
    float* __restrict__ x)
{
  __shared__ u16 LW1[2][8192];
  __shared__ u16 LH[8192];
  __shared__ float sred[256];

  const int tid = threadIdx.x;
  const int lane = tid & 63, wave = tid >> 6;
  const int lr = lane & 15, lg = lane >> 4;
  const int r0 = blockIdx.x << 7;
  const int woff = wave << 5;

  sred[tid] = 0.f;

  stage_img(LW1[0], W1I, wave, lane);                       // chunk 0 in flight

  const int gr0 = r0 + woff + lr;
  bf16x8 aF[2][4];
  ln_load_afrags(x + ((size_t)gr0 << 7), x + ((size_t)(gr0 + 16) << 7), st, lg, aF);

  f32x4 acc2[2][8];
#pragma unroll
  for (int mt = 0; mt < 2; ++mt)
#pragma unroll
    for (int n = 0; n < 8; ++n) acc2[mt][n] = (f32x4){0.f, 0.f, 0.f, 0.f};

  __syncthreads();                                          // chunk 0 ready

#pragma unroll 1
  for (int c = 0; c < 8; ++c) {
    if (c < 7) stage_img(LW1[(c + 1) & 1], W1I + ((c + 1) << 13), wave, lane);
    // gemm1: a1 = A @ W1c
    f32x4 a1[2][4];
    gemm_rA_B64(aF, LW1[c & 1], lr, lg, a1);
    // h = hswish(a1 + b1) -> LH (own-wave rows; same-wave write->read)
    const float* bb1 = b1 + (c << 6);
#pragma unroll
    for (int n = 0; n < 4; ++n) {
      const int hl = (n << 4) + lr;
      const float bb = bb1[hl];
#pragma unroll
      for (int mt = 0; mt < 2; ++mt)
#pragma unroll
        for (int rr = 0; rr < 4; ++rr) {
          const int rl = woff + (mt << 4) + (lg << 2) + rr;
          const float h = a1[mt][n][rr] + bb;
          const float r6 = fminf(fmaxf(h + 3.f, 0.f), 6.f);
          LH[tix64(rl, hl)] = f2bf(h * r6 * (1.f / 6.f));
        }
    }
    // gemm2: acc2 += LH @ W2c (W2 fragments straight from L2)
#pragma unroll
    for (int kk = 0; kk < 2; ++kk) {
      const int ks = (kk << 5) + (lg << 3);
      bf16x8 af2[2], b2f[8];
#pragma unroll
      for (int n = 0; n < 8; ++n)
        b2f[n] = *(const bf16x8*)&W2T[(size_t)((n << 4) + lr) * 512 + (c << 6) + ks];
#pragma unroll
      for (int mt = 0; mt < 2; ++mt)
        af2[mt] = *(const bf16x8*)&LH[tix64(woff + (mt << 4) + lr, ks)];
#pragma unroll
      for (int mt = 0; mt < 2; ++mt)
#pragma unroll
        for (int n = 0; n < 8; ++n)
          acc2[mt][n] = mfma16(af2[mt], b2f[n], acc2[mt][n]);
    }
    __syncthreads();                                        // next chunk ready; LW1 WAR safe
  }

  // epilogue: residual + next LN1 stats
#pragma unroll
  for (int n = 0; n < 8; ++n) {
    const int col = (n << 4) + lr;
    const float bb = b2[col];
    float ssum = 0.f, qsum = 0.f;
#pragma unroll
    for (int mt = 0; mt < 2; ++mt) {
#pragma unroll
      for (int rr = 0; rr < 4; ++rr) {
        const int rl = woff + (mt << 4) + (lg << 2) + rr;
        const size_t gi = ((size_t)(r0 + rl) << 7) + col;
        const float v = acc2[mt][n][rr] + bb + x[gi];
        x[gi] = v;
        ssum += v; qsum += v * v;
      }
    }
    atomicAdd(&sred[col], ssum);
    atomicAdd(&sred[128 + col], qsum);
  }
  __syncthreads();
  atomicAdd(&accum[tid], sred[tid]);
}

// ---------------------------------------------------------------------------
extern "C" void kernel_launch(void* const* d_in, const int* in_sizes, int n_in,
                              void* d_out, int out_size, void* d_ws, size_t ws_size,
                              hipStream_t stream)
{
  const float* img   = (const float*)d_in[0];
  const float* ln1g  = (const float*)d_in[1];
  const float* ln1b  = (const float*)d_in[2];
  const float* Wqkv  = (const float*)d_in[3];
  const float* bqkv  = (const float*)d_in[4];
  const float* Wproj = (const float*)d_in[5];
  const float* bproj = (const float*)d_in[6];
  const float* ln2g  = (const float*)d_in[7];
  const float* ln2b  = (const float*)d_in[8];
  const float* W1    = (const float*)d_in[9];
  const float* b1    = (const float*)d_in[10];
  const float* W2    = (const float*)d_in[11];
  const float* b2    = (const float*)d_in[12];

  char* ws = (char*)d_ws;
  float* x = (float*)ws;                              // 64 MB
  char* wsw = ws + ((size_t)64 << 20);
  u16* WqI = (u16*)wsw;                               // 3*49152
  u16* WpI = WqI + 3 * 49152;                         // 3*16384
  u16* W1I = WpI + 3 * 16384;                         // 3*65536
  u16* W2T = W1I + 3 * 65536;                         // 3*65536
  float* bqp = (float*)(W2T + 3 * 65536);             // 3*384
  float* A   = bqp + 3 * 384;                         // 7*256 stats accumulators
  float* S   = A + 7 * 256;                           // 7*256 fold params

  prep_kernel<<<2309, 256, 0, stream>>>(Wqkv, bqkv, Wproj, W1, W2, WqI, WpI, W1I, W2T, bqp);
  hipMemsetAsync(A, 0, 7 * 256 * sizeof(float), stream);
  tin_kernel<<<2048, 256, 0, stream>>>(img, x, A);
  finalize_kernel<<<1, 128, 0, stream>>>(A, ln1g, ln1b, S);

  for (int d = 0; d < 3; ++d) {
    float* accA = A + (2 * d + 1) * 256;
    float* accF = A + (2 * d + 2) * 256;
    float* st1  = S + (2 * d) * 256;
    float* st2  = S + (2 * d + 1) * 256;
    attn_fused_kernel<<<1024, 256, 0, stream>>>(
        WqI + d * 49152, bqp + d * 384, WpI + d * 16384, bproj + d * 128,
        st1, accA, x);
    finalize_kernel<<<1, 128, 0, stream>>>(accA, ln2g + d * 128, ln2b + d * 128, st2);
    ffn_fused_kernel<<<1024, 256, 0, stream>>>(
        W1I + d * 65536, b1 + d * 512, W2T + d * 65536, b2 + d * 128,
        st2, accF, x);
    if (d < 2)
      finalize_kernel<<<1, 128, 0, stream>>>(accF, ln1g + (d + 1) * 128, ln1b + (d + 1) * 128,
                                             S + (2 * d + 2) * 256);
  }

  tout_kernel<<<2048, 256, 0, stream>>>(x, (float*)d_out);
}